// Round 7
// baseline (194.742 us; speedup 1.0000x reference)
//
#include <hip/hip_runtime.h>
#include <math.h>

// Problem constants
#define NN 256
#define KK 512
#define JJ 6
#define BB 8
#define MPTS 100000
#define NBINS (KK * KK)
// K/(2*pi)
#define KF_SCALE 81.48733086305615f

typedef _Float16 h8 __attribute__((ext_vector_type(8)));

// ---------- device helpers ----------

// Abramowitz & Stegun 9.8.1 / 9.8.2 modified Bessel I0, float
__device__ __forceinline__ float i0f_dev(float x) {
    float ax = fabsf(x);
    if (ax < 3.75f) {
        float t = x / 3.75f; t *= t;
        return 1.0f + t*(3.5156229f + t*(3.0899424f + t*(1.2067492f +
               t*(0.2659732f + t*(0.0360768f + t*0.0045813f)))));
    } else {
        float t = 3.75f / ax;
        return (expf(ax) * rsqrtf(ax)) *
               (0.39894228f + t*(0.01328592f + t*(0.00225319f + t*(-0.00157565f +
                t*(0.00916281f + t*(-0.02057706f + t*(0.02635537f +
                t*(-0.01647633f + t*0.00392377f))))))));
    }
}

__device__ __forceinline__ float kbf(float t, float beta, float inv_i0b) {
    float u = t * (1.0f / 3.0f);       // 2*t/J, J=6
    float q = fmaxf(1.0f - u * u, 0.0f);
    return i0f_dev(beta * sqrtf(q)) * inv_i0b;
}

// order-preserving float<->uint for atomic min/max
__device__ __forceinline__ unsigned fkey(float f) {
    unsigned u = __float_as_uint(f);
    return (u & 0x80000000u) ? ~u : (u | 0x80000000u);
}
__device__ __forceinline__ float funkey(unsigned k) {
    unsigned u = (k & 0x80000000u) ? (k & 0x7FFFFFFFu) : ~k;
    return __uint_as_float(u);
}

// ---------- binning kernels ----------

__global__ __launch_bounds__(256) void count_bins(
    const float2* __restrict__ uv2, int* __restrict__ counts)
{
    int m = blockIdx.x * 256 + threadIdx.x;
    if (m >= MPTS) return;
    float2 u = uv2[m];
    int b0 = (int)floorf(u.x * KF_SCALE) & (KK - 1);
    int b1 = (int)floorf(u.y * KF_SCALE) & (KK - 1);
    atomicAdd(&counts[(b0 << 9) | b1], 1);
}

__global__ __launch_bounds__(1024) void scan1(
    const int* __restrict__ counts, int* __restrict__ offsets, int* __restrict__ bsum)
{
    __shared__ int s[1024];
    int i = blockIdx.x * 1024 + threadIdx.x;
    int v = counts[i];
    s[threadIdx.x] = v;
    for (int off = 1; off < 1024; off <<= 1) {
        __syncthreads();
        int t = (threadIdx.x >= off) ? s[threadIdx.x - off] : 0;
        __syncthreads();
        s[threadIdx.x] += t;
    }
    offsets[i] = s[threadIdx.x] - v;
    if (threadIdx.x == 1023) bsum[blockIdx.x] = s[1023];
}

// scan2 also initializes the min/max atomic cells (runs well before fftB).
__global__ __launch_bounds__(256) void scan2(
    const int* __restrict__ bsum, int* __restrict__ boff,
    unsigned* __restrict__ mmin, unsigned* __restrict__ mmax)
{
    __shared__ int s[256];
    int v = bsum[threadIdx.x];
    s[threadIdx.x] = v;
    if (threadIdx.x < 8)  mmin[threadIdx.x] = 0xFFFFFFFFu;
    else if (threadIdx.x < 16) mmax[threadIdx.x - 8] = 0u;
    for (int off = 1; off < 256; off <<= 1) {
        __syncthreads();
        int t = (threadIdx.x >= off) ? s[threadIdx.x - off] : 0;
        __syncthreads();
        s[threadIdx.x] += t;
    }
    boff[threadIdx.x] = s[threadIdx.x] - v;
}

__global__ __launch_bounds__(1024) void scan3(
    int* __restrict__ offsets, const int* __restrict__ boff)
{
    int i = blockIdx.x * 1024 + threadIdx.x;
    offsets[i] += boff[blockIdx.x];
    if (i == 0) offsets[NBINS] = MPTS;
}

// fill_records: 64B record per point, written to its CSR slot (sorted by bin):
//  [0,12)  w0[6]  f16 axis-0 KB weights
//  [12,24) w1[6]  f16 axis-1 KB weights
//  [24,28) bin1   int (c1 coordinate of the point's bin)
//  [28,32) pad
//  [32,64) y      16 x f16: 8 batches, (re,im) pairs, pre-weighted
__global__ __launch_bounds__(256) void fill_records(
    const float2* __restrict__ uv2,
    const float* __restrict__ y_real, const float* __restrict__ y_imag,
    const float* __restrict__ weights, const int* __restrict__ offsets,
    int* __restrict__ counts, char* __restrict__ rec,
    float beta, float inv_i0b)
{
    int m = blockIdx.x * 256 + threadIdx.x;
    if (m >= MPTS) return;
    float2 u = uv2[m];
    float kf0 = u.x * KF_SCALE;
    float kf1 = u.y * KF_SCALE;
    float f0 = floorf(kf0), f1 = floorf(kf1);
    float fr0 = kf0 - f0, fr1 = kf1 - f1;
    int b1c = (int)f1 & (KK - 1);
    int bin = (((int)f0 & (KK - 1)) << 9) | b1c;
    int old = atomicSub(&counts[bin], 1);
    int slot = offsets[bin] + old - 1;

    _Float16 hw[12];
#pragma unroll
    for (int j = 0; j < JJ; ++j) {
        hw[j]     = (_Float16)kbf((float)(j - 2) - fr0, beta, inv_i0b);
        hw[6 + j] = (_Float16)kbf((float)(j - 2) - fr1, beta, inv_i0b);
    }

    float4 c0v, c1v;
    _Float16* p0 = (_Float16*)&c0v;
    _Float16* p1 = (_Float16*)&c1v;
#pragma unroll
    for (int j = 0; j < 8; ++j) p0[j] = hw[j];        // w0[0..5], w1[0..1]
#pragma unroll
    for (int j = 0; j < 4; ++j) p1[j] = hw[8 + j];    // w1[2..5]
    ((int*)&c1v)[2] = b1c;
    ((int*)&c1v)[3] = 0;

    float wm = weights[m];
    h8 ha, hb;
#pragma unroll
    for (int b = 0; b < 4; ++b) {
        ha[2 * b]     = (_Float16)(y_real[b * MPTS + m] * wm);
        ha[2 * b + 1] = (_Float16)(y_imag[b * MPTS + m] * wm);
        hb[2 * b]     = (_Float16)(y_real[(b + 4) * MPTS + m] * wm);
        hb[2 * b + 1] = (_Float16)(y_imag[(b + 4) * MPTS + m] * wm);
    }

    float4* dst = (float4*)(rec + (size_t)slot * 64);
    dst[0] = c0v;
    dst[1] = c1v;
    dst[2] = *(float4*)&ha;
    dst[3] = *(float4*)&hb;
}

// ---------- gather v4: wave-cooperative row sweep over staged LDS chunks ----
// Wave owns 64 cells (fixed c0, c1 in [c1base, c1base+64)). For each of the 6
// bin-rows, the union of contributing bins is a contiguous CSR span
// [c1base-3, c1base+65] (split in <=2 segments at the mod-512 wrap). The span's
// records are staged into per-wave LDS in 64-point chunks with coalesced
// float4 loads; then all lanes sweep the points together (uniform trip count),
// reading via LDS broadcast + one per-lane f16 weight read.
__global__ __launch_bounds__(256) void gather_grid(
    const int* __restrict__ offsets, const char* __restrict__ rec,
    float* __restrict__ grid)
{
    __shared__ __align__(16) char lds[4][4096];
    int t = threadIdx.x;
    int lane = t & 63;
    int w = t >> 6;
    // XCD-grouped mapping: xcd = blk&7 owns c0 in [64*xcd, 64*xcd+64)
    int j = blockIdx.x;
    int xcd = j & 7;
    int slot = j >> 3;                 // [0,128)
    int c0 = (xcd << 6) + (slot >> 1);
    int half = slot & 1;
    int c1base = (half << 8) + (w << 6);
    int c1 = c1base + lane;

    char* myl = lds[w];

    float aR[BB], aI[BB];
#pragma unroll
    for (int b = 0; b < BB; ++b) { aR[b] = 0.0f; aI[b] = 0.0f; }

    for (int j0 = 0; j0 < JJ; ++j0) {
        int r0 = (c0 - (j0 - 2)) & (KK - 1);
        int rowbase = r0 << 9;
        int lo = c1base - 3, hi = c1base + 65;
        int nseg, sb0, se0, sb1, se1;
        if (lo < 0)        { sb0 = lo + 512; se0 = 511; sb1 = 0; se1 = hi;       nseg = 2; }
        else if (hi > 511) { sb0 = lo;       se0 = 511; sb1 = 0; se1 = hi - 512; nseg = 2; }
        else               { sb0 = lo;       se0 = hi;  sb1 = 0; se1 = 0;        nseg = 1; }

        for (int sgi = 0; sgi < nseg; ++sgi) {
            int bs = sgi ? sb1 : sb0;
            int be = sgi ? se1 : se0;
            int pstart = offsets[rowbase + bs];
            int pend   = offsets[rowbase + be + 1];

            for (int pc = pstart; pc < pend; pc += 64) {
                int cnt = min(64, pend - pc);
                // stage chunk: load q covers points [pc+16q, pc+16q+16)
                int sub = lane & 3;
                int pt0 = pc + (lane >> 2);
#pragma unroll
                for (int q = 0; q < 4; ++q) {
                    int pp = min(pt0 + 16 * q, MPTS - 1);
                    float4 v = *(const float4*)(rec + (size_t)pp * 64 + sub * 16);
                    *(float4*)(myl + q * 1024 + lane * 16) = v;
                }
                for (int jj = 0; jj < cnt; ++jj) {
                    const char* rp = myl + jj * 64;
                    int bin1 = *(const int*)(rp + 24);              // broadcast
                    float w0 = (float)*(const _Float16*)(rp + j0 * 2);
                    int o1u = (c1 - bin1 + 2) & (KK - 1);
                    bool valid = o1u <= 5;
                    int idx = valid ? o1u : 0;
                    float w1 = (float)*(const _Float16*)(rp + 12 + idx * 2);
                    float ww = valid ? w0 * w1 : 0.0f;
                    h8 ya = *(const h8*)(rp + 32);                  // broadcast
                    h8 yb = *(const h8*)(rp + 48);
#pragma unroll
                    for (int b = 0; b < 4; ++b) {
                        aR[b]     += (float)ya[2 * b]     * ww;     // v_fma_mix
                        aI[b]     += (float)ya[2 * b + 1] * ww;
                        aR[b + 4] += (float)yb[2 * b]     * ww;
                        aI[b + 4] += (float)yb[2 * b + 1] * ww;
                    }
                }
            }
        }
    }

    float2* g2 = (float2*)grid;
    int c = (c0 << 9) + c1;
#pragma unroll
    for (int b = 0; b < BB; ++b)
        g2[((size_t)b << 18) + c] = make_float2(aR[b], aI[b]);
}

// ---------- per-wave 512-pt FFT: 8(reg) x 64(lanes via shfl), sign +i ----------
// Input:  lane holds x[brev6(lane) + 64a] in (xr[a], xi[a]).
// Output: lane holds X[d + 8*lane] in (xr[d], xi[d]),
//         X[k] = sum_n x[n] e^{+2*pi*i*n*k/512}.
__device__ __forceinline__ void wave_fft512(float xr[8], float xi[8], int lane)
{
    // ---- in-register FFT8 over a (natural in / natural out, +i) ----
    float a0r = xr[0]+xr[4], a0i = xi[0]+xi[4];
    float a4r = xr[0]-xr[4], a4i = xi[0]-xi[4];
    float a2r = xr[2]+xr[6], a2i = xi[2]+xi[6];
    float a6r = xr[2]-xr[6], a6i = xi[2]-xi[6];
    float a1r = xr[1]+xr[5], a1i = xi[1]+xi[5];
    float a5r = xr[1]-xr[5], a5i = xi[1]-xi[5];
    float a3r = xr[3]+xr[7], a3i = xi[3]+xi[7];
    float a7r = xr[3]-xr[7], a7i = xi[3]-xi[7];
    float b0r = a0r+a2r, b0i = a0i+a2i;
    float b2r = a0r-a2r, b2i = a0i-a2i;
    float b4r = a4r-a6i, b4i = a4i+a6r;    // a4 + i*a6
    float b6r = a4r+a6i, b6i = a4i-a6r;    // a4 - i*a6
    float b1r = a1r+a3r, b1i = a1i+a3i;
    float b3r = a1r-a3r, b3i = a1i-a3i;
    float b5r = a5r-a7i, b5i = a5i+a7r;
    float b7r = a5r+a7i, b7i = a5i-a7r;
    const float S2 = 0.70710678118654752f;
    float w5r = S2*(b5r-b5i), w5i = S2*(b5r+b5i);     // W8^1 * b5, W8 = (S2+i*S2)
    float w7r = -S2*(b7r+b7i), w7i = S2*(b7r-b7i);    // W8^3 * b7
    float y0r = b0r+b1r, y0i = b0i+b1i;
    float y4r = b0r-b1r, y4i = b0i-b1i;
    float y1r = b4r+w5r, y1i = b4i+w5i;
    float y5r = b4r-w5r, y5i = b4i-w5i;
    float y2r = b2r-b3i, y2i = b2i+b3r;    // b2 + i*b3
    float y6r = b2r+b3i, y6i = b2i-b3r;
    float y3r = b6r+w7r, y3i = b6i+w7i;
    float y7r = b6r-w7r, y7i = b6i-w7i;

    // ---- twiddle T[d] = Y[d] * w^(p*d), w = e^{+2pi i p/512}, p = brev6(lane) ----
    int p = __brev((unsigned)lane) >> 26;
    float ang = (float)(2.0 * M_PI / 512.0) * (float)p;
    float c1, s1; sincosf(ang, &s1, &c1);
    float wr = c1, wi = s1, tr;
    xr[0] = y0r; xi[0] = y0i;
    xr[1] = y1r*wr - y1i*wi; xi[1] = y1i*wr + y1r*wi;
    tr = wr*c1 - wi*s1; wi = wr*s1 + wi*c1; wr = tr;
    xr[2] = y2r*wr - y2i*wi; xi[2] = y2i*wr + y2r*wi;
    tr = wr*c1 - wi*s1; wi = wr*s1 + wi*c1; wr = tr;
    xr[3] = y3r*wr - y3i*wi; xi[3] = y3i*wr + y3r*wi;
    tr = wr*c1 - wi*s1; wi = wr*s1 + wi*c1; wr = tr;
    xr[4] = y4r*wr - y4i*wi; xi[4] = y4i*wr + y4r*wi;
    tr = wr*c1 - wi*s1; wi = wr*s1 + wi*c1; wr = tr;
    xr[5] = y5r*wr - y5i*wi; xi[5] = y5i*wr + y5r*wi;
    tr = wr*c1 - wi*s1; wi = wr*s1 + wi*c1; wr = tr;
    xr[6] = y6r*wr - y6i*wi; xi[6] = y6i*wr + y6r*wi;
    tr = wr*c1 - wi*s1; wi = wr*s1 + wi*c1; wr = tr;
    xr[7] = y7r*wr - y7i*wi; xi[7] = y7i*wr + y7r*wi;

    // ---- cross-lane FFT64 over p (DIT, bit-reversed input order in lanes) ----
#pragma unroll
    for (int t = 0; t < 6; ++t) {
        int m = 1 << t;
        int j = lane & (m - 1);
        float wc, wsn;
        sincosf((float)M_PI * (float)j / (float)m, &wsn, &wc);  // e^{+2pi i j/(2m)}
        bool hi = (lane & m) != 0;
#pragma unroll
        for (int d = 0; d < 8; ++d) {
            float pR = __shfl_xor(xr[d], m, 64);
            float pI = __shfl_xor(xi[d], m, 64);
            float bR = hi ? xr[d] : pR;
            float bI = hi ? xi[d] : pI;
            float aR = hi ? pR : xr[d];
            float aI = hi ? pI : xi[d];
            float wbR = wc * bR - wsn * bI;
            float wbI = wc * bI + wsn * bR;
            xr[d] = hi ? aR - wbR : aR + wbR;
            xi[d] = hi ? aI - wbI : aI + wbI;
        }
    }
}

// fftA: k2-transform. 512 blocks x 8 waves; wave = row (b, k1).
// Keeps the 256 fftshift-cropped outputs, transposes via swizzled LDS,
// stores C[b][s2][k1] with 64B-coalesced segments.
__global__ __launch_bounds__(512) void fftA(
    const float2* __restrict__ grid2, float2* __restrict__ C)
{
    __shared__ float sR[2112], sI[2112];   // 8 waves * 264, stride33 swizzle
    int t = threadIdx.x;
    int lane = t & 63;
    int w = t >> 6;
    int b = blockIdx.x & 7;
    int k1base = (blockIdx.x >> 3) << 3;
    int k1 = k1base + w;

    const float2* row = grid2 + ((size_t)b << 18) + ((size_t)k1 << 9);
    int p = __brev((unsigned)lane) >> 26;
    float xr[8], xi[8];
#pragma unroll
    for (int a = 0; a < 8; ++a) {
        float2 v = row[p + (a << 6)];
        xr[a] = v.x; xi[a] = v.y;
    }

    wave_fft512(xr, xi, lane);

    // keep k = d+8*lane in [0,128)U[384,512): lanes <16 or >=48
    bool act = (lane < 16) | (lane >= 48);
    int lpp = (lane < 16) ? lane : (lane - 32);   // [0,32)
    if (act) {
#pragma unroll
        for (int d = 0; d < 8; ++d) {
            int addr = w * 264 + d * 33 + lpp;    // banks (8w+d+lpp)%32: conflict-free
            sR[addr] = xr[d];
            sI[addr] = xi[d];
        }
    }
    __syncthreads();

#pragma unroll
    for (int pp = 0; pp < 4; ++pp) {
        int idx = pp * 512 + t;                   // [0,2048) = 256 s2 x 8 k1
        int kk = idx & 7;
        int s2 = idx >> 3;
        int v = (s2 + 128) & 255;                 // v = 8*lpp + d
        int d = v & 7;
        int lp = v >> 3;
        int addr = kk * 264 + d * 33 + lp;
        C[(((size_t)(b << 8) + s2) << 9) + k1base + kk] = make_float2(sR[addr], sI[addr]);
    }
}

// fftB: k1-transform + apod + fused min/max. 512 blocks x 4 waves;
// wave = row (b, s2). No LDS, no barriers.
__global__ __launch_bounds__(256) void fftB(
    const float2* __restrict__ C, float* __restrict__ img, float beta2,
    unsigned* __restrict__ mmin, unsigned* __restrict__ mmax)
{
    int t = threadIdx.x;
    int lane = t & 63;
    int w = t >> 6;
    int rowid = blockIdx.x * 4 + w;               // [0,2048) = b*256 + s2
    int b = rowid >> 8;
    int s2 = rowid & 255;

    const float2* row = C + ((size_t)rowid << 9);
    int p = __brev((unsigned)lane) >> 26;
    float xr[8], xi[8];
#pragma unroll
    for (int a = 0; a < 8; ++a) {
        float2 v = row[p + (a << 6)];
        xr[a] = v.x; xi[a] = v.y;
    }

    wave_fft512(xr, xi, lane);

    const float XF = (float)(M_PI * (double)JJ / (double)KK);
    const float INVK2 = 1.0f / ((float)KK * (float)KK);
    float ns = (float)(s2 - 128);
    float xfs = XF * ns;
    float asq = beta2 - xfs * xfs;
    float ssq = sqrtf(asq);
    float ds = sinhf(ssq) / ssq;                  // wave-uniform
    float sbase = INVK2 / ds;

    bool act = (lane < 16) | (lane >= 48);
    int lpp = (lane < 16) ? lane : (lane - 32);
    float lmin = 1e30f, lmax = -1e30f;
    if (act) {
#pragma unroll
        for (int d = 0; d < 8; ++d) {
            int r = (8 * lpp + d + 128) & 255;
            float nr = (float)(r - 128);
            float xfr = XF * nr;
            float arq = beta2 - xfr * xfr;
            float srq = sqrtf(arq);
            float dr = sinhf(srq) / srq;
            float o = xr[d] * sbase / dr;
            img[((size_t)b << 16) + (r << 8) + s2] = o;
            lmin = fminf(lmin, o);
            lmax = fmaxf(lmax, o);
        }
    }
#pragma unroll
    for (int off = 32; off >= 1; off >>= 1) {
        lmin = fminf(lmin, __shfl_xor(lmin, off, 64));
        lmax = fmaxf(lmax, __shfl_xor(lmax, off, 64));
    }
    if (lane == 0) {
        atomicMin(&mmin[b], fkey(lmin));
        atomicMax(&mmax[b], fkey(lmax));
    }
}

__global__ __launch_bounds__(256) void norm_k(
    const float* __restrict__ img, const unsigned* __restrict__ mmin,
    const unsigned* __restrict__ mmax, float* __restrict__ out)
{
    int i = blockIdx.x * 256 + threadIdx.x;
    int b = i >> 16;
    float mn = funkey(mmin[b]), mx = funkey(mmax[b]);
    out[i] = (img[i] - mn) / (mx - mn);
}

// ---------- host ----------

static double i0_host(double x) {
    double sum = 1.0, term = 1.0;
    double q = x * x * 0.25;
    for (int k = 1; k < 80; ++k) {
        term *= q / ((double)k * (double)k);
        sum += term;
        if (term < sum * 1e-17) break;
    }
    return sum;
}

extern "C" void kernel_launch(void* const* d_in, const int* in_sizes, int n_in,
                              void* d_out, int out_size, void* d_ws, size_t ws_size,
                              hipStream_t stream)
{
    const float* y_real  = (const float*)d_in[0];
    const float* y_imag  = (const float*)d_in[1];
    const float* weights = (const float*)d_in[2];
    const float* uv      = (const float*)d_in[3];
    float* out = (float*)d_out;

    char* W = (char*)d_ws;
    // Aliased live ranges (peak ~24.4 MB):
    //  W[0,16M): counts/bsum/boff (pre-gather) -> grid (gather->fftA) -> img [0,2M)
    //  A=W+16M:  rec [0,6.4M) + offsets [6.4M,7.45M) (bin->gather)
    //            -> C [0,8M) (fftA->fftB);  mm at [8.4M,8.4M+96) (scan2->norm)
    float*    grid    = (float*)W;                         // 16 MB
    int*      counts  = (int*)W;                           // 1 MB (aliases grid)
    int*      bsum    = (int*)(W + 0x100000);
    int*      boff    = (int*)(W + 0x100400);
    float*    img     = (float*)W;                         // 2 MB (aliases grid)
    char*     A       = W + (size_t)16 * 1024 * 1024;
    char*     rec     = A;                                 // 6,400,000 B
    int*      offsets = (int*)(A + 6400000);               // 1,048,580 B
    float2*   C       = (float2*)A;                        // 8 MB (aliases rec)
    unsigned* mmin    = (unsigned*)(A + 8400000);          // 32 B
    unsigned* mmax    = (unsigned*)(A + 8400064);          // 32 B

    double beta_d = M_PI * sqrt(19.45);   // BETA with alpha=2
    float beta = (float)beta_d;
    float inv_i0b = (float)(1.0 / i0_host(beta_d));
    float beta2 = (float)(beta_d * beta_d);

    hipMemsetAsync(counts, 0, NBINS * sizeof(int), stream);

    count_bins<<<(MPTS + 255) / 256, 256, 0, stream>>>((const float2*)uv, counts);

    scan1<<<256, 1024, 0, stream>>>(counts, offsets, bsum);
    scan2<<<1, 256, 0, stream>>>(bsum, boff, mmin, mmax);
    scan3<<<256, 1024, 0, stream>>>(offsets, boff);

    fill_records<<<(MPTS + 255) / 256, 256, 0, stream>>>(
        (const float2*)uv, y_real, y_imag, weights, offsets, counts,
        rec, beta, inv_i0b);

    gather_grid<<<1024, 256, 0, stream>>>(offsets, rec, grid);

    fftA<<<512, 512, 0, stream>>>((const float2*)grid, C);

    fftB<<<512, 256, 0, stream>>>(C, img, beta2, mmin, mmax);

    norm_k<<<(BB * NN * NN) / 256, 256, 0, stream>>>(img, mmin, mmax, out);
}

// Round 8
// 161.638 us; speedup vs baseline: 1.2048x; 1.2048x over previous
//
#include <hip/hip_runtime.h>
#include <math.h>

// Problem constants
#define NN 256
#define KK 512
#define JJ 6
#define BB 8
#define MPTS 100000
#define NBINS (KK * KK)
// K/(2*pi)
#define KF_SCALE 81.48733086305615f

typedef _Float16 h8 __attribute__((ext_vector_type(8)));

// ---------- device helpers ----------

// Abramowitz & Stegun 9.8.1 / 9.8.2 modified Bessel I0, float
__device__ __forceinline__ float i0f_dev(float x) {
    float ax = fabsf(x);
    if (ax < 3.75f) {
        float t = x / 3.75f; t *= t;
        return 1.0f + t*(3.5156229f + t*(3.0899424f + t*(1.2067492f +
               t*(0.2659732f + t*(0.0360768f + t*0.0045813f)))));
    } else {
        float t = 3.75f / ax;
        return (expf(ax) * rsqrtf(ax)) *
               (0.39894228f + t*(0.01328592f + t*(0.00225319f + t*(-0.00157565f +
                t*(0.00916281f + t*(-0.02057706f + t*(0.02635537f +
                t*(-0.01647633f + t*0.00392377f))))))));
    }
}

__device__ __forceinline__ float kbf(float t, float beta, float inv_i0b) {
    float u = t * (1.0f / 3.0f);       // 2*t/J, J=6
    float q = fmaxf(1.0f - u * u, 0.0f);
    return i0f_dev(beta * sqrtf(q)) * inv_i0b;
}

// order-preserving float<->uint for atomic min/max
__device__ __forceinline__ unsigned fkey(float f) {
    unsigned u = __float_as_uint(f);
    return (u & 0x80000000u) ? ~u : (u | 0x80000000u);
}
__device__ __forceinline__ float funkey(unsigned k) {
    unsigned u = (k & 0x80000000u) ? (k & 0x7FFFFFFFu) : ~k;
    return __uint_as_float(u);
}

// ---------- binning kernels ----------

__global__ __launch_bounds__(256) void count_bins(
    const float2* __restrict__ uv2, int* __restrict__ counts)
{
    int m = blockIdx.x * 256 + threadIdx.x;
    if (m >= MPTS) return;
    float2 u = uv2[m];
    int b0 = (int)floorf(u.x * KF_SCALE) & (KK - 1);
    int b1 = (int)floorf(u.y * KF_SCALE) & (KK - 1);
    atomicAdd(&counts[(b0 << 9) | b1], 1);
}

__global__ __launch_bounds__(1024) void scan1(
    const int* __restrict__ counts, int* __restrict__ offsets, int* __restrict__ bsum)
{
    __shared__ int s[1024];
    int i = blockIdx.x * 1024 + threadIdx.x;
    int v = counts[i];
    s[threadIdx.x] = v;
    for (int off = 1; off < 1024; off <<= 1) {
        __syncthreads();
        int t = (threadIdx.x >= off) ? s[threadIdx.x - off] : 0;
        __syncthreads();
        s[threadIdx.x] += t;
    }
    offsets[i] = s[threadIdx.x] - v;
    if (threadIdx.x == 1023) bsum[blockIdx.x] = s[1023];
}

// scan2 also initializes the min/max atomic cells (runs well before fftB).
__global__ __launch_bounds__(256) void scan2(
    const int* __restrict__ bsum, int* __restrict__ boff,
    unsigned* __restrict__ mmin, unsigned* __restrict__ mmax)
{
    __shared__ int s[256];
    int v = bsum[threadIdx.x];
    s[threadIdx.x] = v;
    if (threadIdx.x < 8)  mmin[threadIdx.x] = 0xFFFFFFFFu;
    else if (threadIdx.x < 16) mmax[threadIdx.x - 8] = 0u;
    for (int off = 1; off < 256; off <<= 1) {
        __syncthreads();
        int t = (threadIdx.x >= off) ? s[threadIdx.x - off] : 0;
        __syncthreads();
        s[threadIdx.x] += t;
    }
    boff[threadIdx.x] = s[threadIdx.x] - v;
}

__global__ __launch_bounds__(1024) void scan3(
    int* __restrict__ offsets, const int* __restrict__ boff)
{
    int i = blockIdx.x * 1024 + threadIdx.x;
    offsets[i] += boff[blockIdx.x];
    if (i == 0) offsets[NBINS] = MPTS;
}

// fill_records: 64B record per point, written to its CSR slot (sorted by bin):
//  [0,12)  w0[6]  f16 axis-0 KB weights
//  [12,24) w1[6]  f16 axis-1 KB weights
//  [24,28) bin1   int (c1 coordinate of the point's bin)
//  [28,32) pad
//  [32,64) y      16 x f16: 8 batches, (re,im) pairs, pre-weighted
__global__ __launch_bounds__(256) void fill_records(
    const float2* __restrict__ uv2,
    const float* __restrict__ y_real, const float* __restrict__ y_imag,
    const float* __restrict__ weights, const int* __restrict__ offsets,
    int* __restrict__ counts, char* __restrict__ rec,
    float beta, float inv_i0b)
{
    int m = blockIdx.x * 256 + threadIdx.x;
    if (m >= MPTS) return;
    float2 u = uv2[m];
    float kf0 = u.x * KF_SCALE;
    float kf1 = u.y * KF_SCALE;
    float f0 = floorf(kf0), f1 = floorf(kf1);
    float fr0 = kf0 - f0, fr1 = kf1 - f1;
    int b1c = (int)f1 & (KK - 1);
    int bin = (((int)f0 & (KK - 1)) << 9) | b1c;
    int old = atomicSub(&counts[bin], 1);
    int slot = offsets[bin] + old - 1;

    _Float16 hw[12];
#pragma unroll
    for (int j = 0; j < JJ; ++j) {
        hw[j]     = (_Float16)kbf((float)(j - 2) - fr0, beta, inv_i0b);
        hw[6 + j] = (_Float16)kbf((float)(j - 2) - fr1, beta, inv_i0b);
    }

    float4 c0v, c1v;
    _Float16* p0 = (_Float16*)&c0v;
    _Float16* p1 = (_Float16*)&c1v;
#pragma unroll
    for (int j = 0; j < 8; ++j) p0[j] = hw[j];        // w0[0..5], w1[0..1]
#pragma unroll
    for (int j = 0; j < 4; ++j) p1[j] = hw[8 + j];    // w1[2..5]
    ((int*)&c1v)[2] = b1c;
    ((int*)&c1v)[3] = 0;

    float wm = weights[m];
    h8 ha, hb;
#pragma unroll
    for (int b = 0; b < 4; ++b) {
        ha[2 * b]     = (_Float16)(y_real[b * MPTS + m] * wm);
        ha[2 * b + 1] = (_Float16)(y_imag[b * MPTS + m] * wm);
        hb[2 * b]     = (_Float16)(y_real[(b + 4) * MPTS + m] * wm);
        hb[2 * b + 1] = (_Float16)(y_imag[(b + 4) * MPTS + m] * wm);
    }

    float4* dst = (float4*)(rec + (size_t)slot * 64);
    dst[0] = c0v;
    dst[1] = c1v;
    dst[2] = *(float4*)&ha;
    dst[3] = *(float4*)&hb;
}

// ---------- gather v5: coalesced LDS staging + per-lane sweep ----------
// Wave owns 64 cells (fixed c0, c1 = c1base+lane). Per bin-row j0, the wave's
// span [c1base-3, c1base+65] (<=2 wrap segments) is staged into per-wave LDS
// (80B padded stride -> low bank conflicts) with coalesced float4 loads; then
// each lane sweeps only ITS OWN CSR sub-range [pA,pB) from LDS. This keeps
// v4's coalesced global traffic but v3's minimal per-lane work.
__global__ __launch_bounds__(256) void gather_grid(
    const int* __restrict__ offsets, const char* __restrict__ rec,
    float* __restrict__ grid)
{
    __shared__ __align__(16) char lds[4][5120];   // 64 pts x 80B per wave
    int t = threadIdx.x;
    int lane = t & 63;
    int w = t >> 6;
    // XCD-grouped mapping: xcd = blk&7 owns c0 in [64*xcd, 64*xcd+64)
    int j = blockIdx.x;
    int xcd = j & 7;
    int slot = j >> 3;                 // [0,128)
    int c0 = (xcd << 6) + (slot >> 1);
    int half = slot & 1;
    int c1base = (half << 8) + (w << 6);
    int c1 = c1base + lane;            // actual column, [0,512)
    int wa = c1 - 3, wb = c1 + 2;      // lane's bin window (unwrapped)

    char* myl = lds[w];

    float aR[BB], aI[BB];
#pragma unroll
    for (int b = 0; b < BB; ++b) { aR[b] = 0.0f; aI[b] = 0.0f; }

    for (int j0 = 0; j0 < JJ; ++j0) {
        int r0 = (c0 - (j0 - 2)) & (KK - 1);
        int rowbase = r0 << 9;
        int lo = c1base - 3, hi = c1base + 65;
        // wave span split into <=2 monotone segments (unwrapped coords)
        int nseg, ga0, gb0, ga1, gb1;
        if (lo < 0)        { ga0 = lo; gb0 = -1;  ga1 = 0;   gb1 = hi; nseg = 2; }
        else if (hi > 511) { ga0 = lo; gb0 = 511; ga1 = 512; gb1 = hi; nseg = 2; }
        else               { ga0 = lo; gb0 = hi;  ga1 = 0;   gb1 = 0;  nseg = 1; }

        for (int sgi = 0; sgi < nseg; ++sgi) {
            int ga = sgi ? ga1 : ga0;
            int gb = sgi ? gb1 : gb0;
            int pstart = offsets[rowbase + (ga & 511)];          // wave-uniform
            int pend   = offsets[rowbase + ((gb & 511) + 1)];    // wave-uniform
            // per-lane window intersect with this segment
            int ia = max(wa, ga), ib = min(wb, gb);
            bool has = ia <= ib;
            int pA = has ? offsets[rowbase + (ia & 511)] : 0;
            int pB = has ? ((ib == gb) ? pend
                                       : offsets[rowbase + ((ib + 1) & 511)]) : 0;

            for (int pc = pstart; pc < pend; pc += 64) {
                int cnt = min(64, pend - pc);
                // stage chunk (coalesced): q covers points [pc+16q, pc+16q+16)
                int sub = lane & 3;
                int prow = lane >> 2;
#pragma unroll
                for (int q = 0; q < 4; ++q) {
                    if (16 * q < cnt) {
                        int pp = min(pc + prow + 16 * q, MPTS - 1);
                        float4 v = *(const float4*)(rec + (size_t)pp * 64 + sub * 16);
                        *(float4*)(myl + (prow + 16 * q) * 80 + sub * 16) = v;
                    }
                }
                // per-lane sweep of its own range within the chunk
                int pLo = max(pA, pc), pHi = min(pB, pc + cnt);
                for (int p = pLo; p < pHi; ++p) {
                    const char* rp = myl + (p - pc) * 80;
                    int bin1 = *(const int*)(rp + 24);
                    int idx = (c1 - bin1 + 2) & 511;   // wrap-exact o1+2
                    bool ok = idx <= 5;
                    idx = ok ? idx : 0;
                    float w0 = (float)*(const _Float16*)(rp + j0 * 2);
                    float w1 = (float)*(const _Float16*)(rp + 12 + idx * 2);
                    float ww = ok ? w0 * w1 : 0.0f;
                    h8 ya = *(const h8*)(rp + 32);
                    h8 yb = *(const h8*)(rp + 48);
#pragma unroll
                    for (int b = 0; b < 4; ++b) {
                        aR[b]     += (float)ya[2 * b]     * ww;   // v_fma_mix
                        aI[b]     += (float)ya[2 * b + 1] * ww;
                        aR[b + 4] += (float)yb[2 * b]     * ww;
                        aI[b + 4] += (float)yb[2 * b + 1] * ww;
                    }
                }
            }
        }
    }

    float2* g2 = (float2*)grid;
    int c = (c0 << 9) + c1;
#pragma unroll
    for (int b = 0; b < BB; ++b)
        g2[((size_t)b << 18) + c] = make_float2(aR[b], aI[b]);
}

// ---------- per-wave 512-pt FFT: 8(reg) x 64(lanes via shfl), sign +i ----------
// Input:  lane holds x[brev6(lane) + 64a] in (xr[a], xi[a]).
// Output: lane holds X[d + 8*lane] in (xr[d], xi[d]),
//         X[k] = sum_n x[n] e^{+2*pi*i*n*k/512}.
__device__ __forceinline__ void wave_fft512(float xr[8], float xi[8], int lane)
{
    // ---- in-register FFT8 over a (natural in / natural out, +i) ----
    float a0r = xr[0]+xr[4], a0i = xi[0]+xi[4];
    float a4r = xr[0]-xr[4], a4i = xi[0]-xi[4];
    float a2r = xr[2]+xr[6], a2i = xi[2]+xi[6];
    float a6r = xr[2]-xr[6], a6i = xi[2]-xi[6];
    float a1r = xr[1]+xr[5], a1i = xi[1]+xi[5];
    float a5r = xr[1]-xr[5], a5i = xi[1]-xi[5];
    float a3r = xr[3]+xr[7], a3i = xi[3]+xi[7];
    float a7r = xr[3]-xr[7], a7i = xi[3]-xi[7];
    float b0r = a0r+a2r, b0i = a0i+a2i;
    float b2r = a0r-a2r, b2i = a0i-a2i;
    float b4r = a4r-a6i, b4i = a4i+a6r;    // a4 + i*a6
    float b6r = a4r+a6i, b6i = a4i-a6r;    // a4 - i*a6
    float b1r = a1r+a3r, b1i = a1i+a3i;
    float b3r = a1r-a3r, b3i = a1i-a3i;
    float b5r = a5r-a7i, b5i = a5i+a7r;
    float b7r = a5r+a7i, b7i = a5i-a7r;
    const float S2 = 0.70710678118654752f;
    float w5r = S2*(b5r-b5i), w5i = S2*(b5r+b5i);     // W8^1 * b5
    float w7r = -S2*(b7r+b7i), w7i = S2*(b7r-b7i);    // W8^3 * b7
    float y0r = b0r+b1r, y0i = b0i+b1i;
    float y4r = b0r-b1r, y4i = b0i-b1i;
    float y1r = b4r+w5r, y1i = b4i+w5i;
    float y5r = b4r-w5r, y5i = b4i-w5i;
    float y2r = b2r-b3i, y2i = b2i+b3r;    // b2 + i*b3
    float y6r = b2r+b3i, y6i = b2i-b3r;
    float y3r = b6r+w7r, y3i = b6i+w7i;
    float y7r = b6r-w7r, y7i = b6i-w7i;

    // ---- twiddle T[d] = Y[d] * w^(p*d), w = e^{+2pi i p/512}, p = brev6(lane) ----
    int p = __brev((unsigned)lane) >> 26;
    float ang = (float)(2.0 * M_PI / 512.0) * (float)p;
    float c1, s1; sincosf(ang, &s1, &c1);
    float wr = c1, wi = s1, tr;
    xr[0] = y0r; xi[0] = y0i;
    xr[1] = y1r*wr - y1i*wi; xi[1] = y1i*wr + y1r*wi;
    tr = wr*c1 - wi*s1; wi = wr*s1 + wi*c1; wr = tr;
    xr[2] = y2r*wr - y2i*wi; xi[2] = y2i*wr + y2r*wi;
    tr = wr*c1 - wi*s1; wi = wr*s1 + wi*c1; wr = tr;
    xr[3] = y3r*wr - y3i*wi; xi[3] = y3i*wr + y3r*wi;
    tr = wr*c1 - wi*s1; wi = wr*s1 + wi*c1; wr = tr;
    xr[4] = y4r*wr - y4i*wi; xi[4] = y4i*wr + y4r*wi;
    tr = wr*c1 - wi*s1; wi = wr*s1 + wi*c1; wr = tr;
    xr[5] = y5r*wr - y5i*wi; xi[5] = y5i*wr + y5r*wi;
    tr = wr*c1 - wi*s1; wi = wr*s1 + wi*c1; wr = tr;
    xr[6] = y6r*wr - y6i*wi; xi[6] = y6i*wr + y6r*wi;
    tr = wr*c1 - wi*s1; wi = wr*s1 + wi*c1; wr = tr;
    xr[7] = y7r*wr - y7i*wi; xi[7] = y7i*wr + y7r*wi;

    // ---- cross-lane FFT64 over p (DIT, bit-reversed input order in lanes) ----
#pragma unroll
    for (int t = 0; t < 6; ++t) {
        int m = 1 << t;
        int j = lane & (m - 1);
        float wc, wsn;
        sincosf((float)M_PI * (float)j / (float)m, &wsn, &wc);  // e^{+2pi i j/(2m)}
        bool hi = (lane & m) != 0;
#pragma unroll
        for (int d = 0; d < 8; ++d) {
            float pR = __shfl_xor(xr[d], m, 64);
            float pI = __shfl_xor(xi[d], m, 64);
            float bR = hi ? xr[d] : pR;
            float bI = hi ? xi[d] : pI;
            float aR = hi ? pR : xr[d];
            float aI = hi ? pI : xi[d];
            float wbR = wc * bR - wsn * bI;
            float wbI = wc * bI + wsn * bR;
            xr[d] = hi ? aR - wbR : aR + wbR;
            xi[d] = hi ? aI - wbI : aI + wbI;
        }
    }
}

// fftA: k2-transform. 512 blocks x 8 waves; wave = row (b, k1).
// Keeps the 256 fftshift-cropped outputs, transposes via swizzled LDS,
// stores C[b][s2][k1] with 64B-coalesced segments.
__global__ __launch_bounds__(512) void fftA(
    const float2* __restrict__ grid2, float2* __restrict__ C)
{
    __shared__ float sR[2112], sI[2112];   // 8 waves * 264, stride33 swizzle
    int t = threadIdx.x;
    int lane = t & 63;
    int w = t >> 6;
    int b = blockIdx.x & 7;
    int k1base = (blockIdx.x >> 3) << 3;
    int k1 = k1base + w;

    const float2* row = grid2 + ((size_t)b << 18) + ((size_t)k1 << 9);
    int p = __brev((unsigned)lane) >> 26;
    float xr[8], xi[8];
#pragma unroll
    for (int a = 0; a < 8; ++a) {
        float2 v = row[p + (a << 6)];
        xr[a] = v.x; xi[a] = v.y;
    }

    wave_fft512(xr, xi, lane);

    // keep k = d+8*lane in [0,128)U[384,512): lanes <16 or >=48
    bool act = (lane < 16) | (lane >= 48);
    int lpp = (lane < 16) ? lane : (lane - 32);   // [0,32)
    if (act) {
#pragma unroll
        for (int d = 0; d < 8; ++d) {
            int addr = w * 264 + d * 33 + lpp;    // conflict-free swizzle
            sR[addr] = xr[d];
            sI[addr] = xi[d];
        }
    }
    __syncthreads();

#pragma unroll
    for (int pp = 0; pp < 4; ++pp) {
        int idx = pp * 512 + t;                   // [0,2048) = 256 s2 x 8 k1
        int kk = idx & 7;
        int s2 = idx >> 3;
        int v = (s2 + 128) & 255;                 // v = 8*lpp + d
        int d = v & 7;
        int lp = v >> 3;
        int addr = kk * 264 + d * 33 + lp;
        C[(((size_t)(b << 8) + s2) << 9) + k1base + kk] = make_float2(sR[addr], sI[addr]);
    }
}

// fftB: k1-transform + apod + fused min/max. 512 blocks x 4 waves;
// wave = row (b, s2). No LDS, no barriers. Stores img TRANSPOSED
// (imgT[b][s2][r]) so each lane writes 2 contiguous float4 (wave = 1KB run).
__global__ __launch_bounds__(256) void fftB(
    const float2* __restrict__ C, float* __restrict__ imgT, float beta2,
    unsigned* __restrict__ mmin, unsigned* __restrict__ mmax)
{
    int t = threadIdx.x;
    int lane = t & 63;
    int w = t >> 6;
    int rowid = blockIdx.x * 4 + w;               // [0,2048) = b*256 + s2
    int b = rowid >> 8;
    int s2 = rowid & 255;

    const float2* row = C + ((size_t)rowid << 9);
    int p = __brev((unsigned)lane) >> 26;
    float xr[8], xi[8];
#pragma unroll
    for (int a = 0; a < 8; ++a) {
        float2 v = row[p + (a << 6)];
        xr[a] = v.x; xi[a] = v.y;
    }

    wave_fft512(xr, xi, lane);

    const float XF = (float)(M_PI * (double)JJ / (double)KK);
    const float INVK2 = 1.0f / ((float)KK * (float)KK);
    float ns = (float)(s2 - 128);
    float xfs = XF * ns;
    float asq = beta2 - xfs * xfs;
    float ssq = sqrtf(asq);
    float ds = sinhf(ssq) / ssq;                  // wave-uniform
    float sbase = INVK2 / ds;

    bool act = (lane < 16) | (lane >= 48);
    int lpp = (lane < 16) ? lane : (lane - 32);
    float lmin = 1e30f, lmax = -1e30f;
    if (act) {
        float vals[8];
#pragma unroll
        for (int d = 0; d < 8; ++d) {
            int r = (8 * lpp + d + 128) & 255;
            float nr = (float)(r - 128);
            float xfr = XF * nr;
            float arq = beta2 - xfr * xfr;
            float srq = sqrtf(arq);
            float dr = sinhf(srq) / srq;
            float o = xr[d] * sbase / dr;
            vals[d] = o;
            lmin = fminf(lmin, o);
            lmax = fmaxf(lmax, o);
        }
        // 8-run never straddles the mod-256 wrap (8 | 256)
        int r0run = (8 * lpp + 128) & 255;
        float4* dst = (float4*)(imgT + ((size_t)b << 16) + (s2 << 8) + r0run);
        dst[0] = make_float4(vals[0], vals[1], vals[2], vals[3]);
        dst[1] = make_float4(vals[4], vals[5], vals[6], vals[7]);
    }
#pragma unroll
    for (int off = 32; off >= 1; off >>= 1) {
        lmin = fminf(lmin, __shfl_xor(lmin, off, 64));
        lmax = fmaxf(lmax, __shfl_xor(lmax, off, 64));
    }
    if (lane == 0) {
        atomicMin(&mmin[b], fkey(lmin));
        atomicMax(&mmax[b], fkey(lmax));
    }
}

// norm_t: normalize + transpose imgT[b][s2][r] -> out[b][r][s2].
// 64x64 LDS tiles, both global phases fully coalesced, stride-65 conflict-free.
__global__ __launch_bounds__(256) void norm_t(
    const float* __restrict__ imgT, const unsigned* __restrict__ mmin,
    const unsigned* __restrict__ mmax, float* __restrict__ out)
{
    __shared__ float tile[64][65];
    int b = blockIdx.x >> 4;
    int tl = blockIdx.x & 15;
    int r0 = (tl & 3) << 6;
    int s0 = (tl >> 2) << 6;
    int tr = threadIdx.x & 63;
    int ts = threadIdx.x >> 6;        // [0,4)

    const float* src = imgT + ((size_t)b << 16);
#pragma unroll
    for (int q = 0; q < 16; ++q) {
        int s2 = s0 + (q << 2) + ts;
        tile[s2 - s0][tr] = src[(s2 << 8) + r0 + tr];
    }
    __syncthreads();

    float mn = funkey(mmin[b]);
    float inv = 1.0f / (funkey(mmax[b]) - mn);
    float* dst = out + ((size_t)b << 16);
#pragma unroll
    for (int q = 0; q < 16; ++q) {
        int r = r0 + (q << 2) + ts;
        dst[(r << 8) + s0 + tr] = (tile[tr][r - r0] - mn) * inv;
    }
}

// ---------- host ----------

static double i0_host(double x) {
    double sum = 1.0, term = 1.0;
    double q = x * x * 0.25;
    for (int k = 1; k < 80; ++k) {
        term *= q / ((double)k * (double)k);
        sum += term;
        if (term < sum * 1e-17) break;
    }
    return sum;
}

extern "C" void kernel_launch(void* const* d_in, const int* in_sizes, int n_in,
                              void* d_out, int out_size, void* d_ws, size_t ws_size,
                              hipStream_t stream)
{
    const float* y_real  = (const float*)d_in[0];
    const float* y_imag  = (const float*)d_in[1];
    const float* weights = (const float*)d_in[2];
    const float* uv      = (const float*)d_in[3];
    float* out = (float*)d_out;

    char* W = (char*)d_ws;
    // Aliased live ranges (peak ~24.4 MB):
    //  W[0,16M): counts/bsum/boff (pre-gather) -> grid (gather->fftA) -> imgT [0,2M)
    //  A=W+16M:  rec [0,6.4M) + offsets [6.4M,7.45M) (bin->gather)
    //            -> C [0,8M) (fftA->fftB);  mm at [8.4M,8.4M+96) (scan2->norm)
    float*    grid    = (float*)W;                         // 16 MB
    int*      counts  = (int*)W;                           // 1 MB (aliases grid)
    int*      bsum    = (int*)(W + 0x100000);
    int*      boff    = (int*)(W + 0x100400);
    float*    imgT    = (float*)W;                         // 2 MB (aliases grid)
    char*     A       = W + (size_t)16 * 1024 * 1024;
    char*     rec     = A;                                 // 6,400,000 B
    int*      offsets = (int*)(A + 6400000);               // 1,048,580 B
    float2*   C       = (float2*)A;                        // 8 MB (aliases rec)
    unsigned* mmin    = (unsigned*)(A + 8400000);          // 32 B
    unsigned* mmax    = (unsigned*)(A + 8400064);          // 32 B

    double beta_d = M_PI * sqrt(19.45);   // BETA with alpha=2
    float beta = (float)beta_d;
    float inv_i0b = (float)(1.0 / i0_host(beta_d));
    float beta2 = (float)(beta_d * beta_d);

    hipMemsetAsync(counts, 0, NBINS * sizeof(int), stream);

    count_bins<<<(MPTS + 255) / 256, 256, 0, stream>>>((const float2*)uv, counts);

    scan1<<<256, 1024, 0, stream>>>(counts, offsets, bsum);
    scan2<<<1, 256, 0, stream>>>(bsum, boff, mmin, mmax);
    scan3<<<256, 1024, 0, stream>>>(offsets, boff);

    fill_records<<<(MPTS + 255) / 256, 256, 0, stream>>>(
        (const float2*)uv, y_real, y_imag, weights, offsets, counts,
        rec, beta, inv_i0b);

    gather_grid<<<1024, 256, 0, stream>>>(offsets, rec, grid);

    fftA<<<512, 512, 0, stream>>>((const float2*)grid, C);

    fftB<<<512, 256, 0, stream>>>(C, imgT, beta2, mmin, mmax);

    norm_t<<<128, 256, 0, stream>>>(imgT, mmin, mmax, out);
}

// Round 10
// 159.500 us; speedup vs baseline: 1.2210x; 1.0134x over previous
//
#include <hip/hip_runtime.h>
#include <math.h>

// Problem constants
#define NN 256
#define KK 512
#define JJ 6
#define BB 8
#define MPTS 100000
#define NBINS (KK * KK)
// K/(2*pi)
#define KF_SCALE 81.48733086305615f

typedef _Float16 h8 __attribute__((ext_vector_type(8)));

// ---------- device helpers ----------

// Abramowitz & Stegun 9.8.1 / 9.8.2 modified Bessel I0, float
__device__ __forceinline__ float i0f_dev(float x) {
    float ax = fabsf(x);
    if (ax < 3.75f) {
        float t = x / 3.75f; t *= t;
        return 1.0f + t*(3.5156229f + t*(3.0899424f + t*(1.2067492f +
               t*(0.2659732f + t*(0.0360768f + t*0.0045813f)))));
    } else {
        float t = 3.75f / ax;
        return (expf(ax) * rsqrtf(ax)) *
               (0.39894228f + t*(0.01328592f + t*(0.00225319f + t*(-0.00157565f +
                t*(0.00916281f + t*(-0.02057706f + t*(0.02635537f +
                t*(-0.01647633f + t*0.00392377f))))))));
    }
}

__device__ __forceinline__ float kbf(float t, float beta, float inv_i0b) {
    float u = t * (1.0f / 3.0f);       // 2*t/J, J=6
    float q = fmaxf(1.0f - u * u, 0.0f);
    return i0f_dev(beta * sqrtf(q)) * inv_i0b;
}

// order-preserving float<->uint for atomic min/max
__device__ __forceinline__ unsigned fkey(float f) {
    unsigned u = __float_as_uint(f);
    return (u & 0x80000000u) ? ~u : (u | 0x80000000u);
}
__device__ __forceinline__ float funkey(unsigned k) {
    unsigned u = (k & 0x80000000u) ? (k & 0x7FFFFFFFu) : ~k;
    return __uint_as_float(u);
}

// inclusive wave scan (64 lanes)
__device__ __forceinline__ int wave_scan(int x, int lane) {
#pragma unroll
    for (int off = 1; off < 64; off <<= 1) {
        int y = __shfl_up(x, off, 64);
        if (lane >= off) x += y;
    }
    return x;
}

// ---------- binning kernels ----------

// count_bins also initializes the min/max atomic cells (used much later by fftB).
__global__ __launch_bounds__(256) void count_bins(
    const float2* __restrict__ uv2, int* __restrict__ counts,
    unsigned* __restrict__ mmin, unsigned* __restrict__ mmax)
{
    int m = blockIdx.x * 256 + threadIdx.x;
    if (m < 8) mmin[m] = 0xFFFFFFFFu;
    else if (m < 16) mmax[m - 8] = 0u;
    if (m >= MPTS) return;
    float2 u = uv2[m];
    int b0 = (int)floorf(u.x * KF_SCALE) & (KK - 1);
    int b1 = (int)floorf(u.y * KF_SCALE) & (KK - 1);
    atomicAdd(&counts[(b0 << 9) | b1], 1);
}

// Single-pass decoupled-lookback exclusive scan of counts[262144] -> offsets.
// 256 blocks x 1024 threads (all co-resident: 256 blocks <= 256 CUs, so the
// lookback spin cannot deadlock and is dispatch-order-independent).
// desc[i] = (value << 2) | flag; flag: 0=invalid, 1=aggregate, 2=inclusive.
// desc must be zeroed (covered by the counts memset).
__global__ __launch_bounds__(1024) void scan_k(
    const int* __restrict__ counts, int* __restrict__ offsets,
    unsigned long long* __restrict__ desc)
{
    __shared__ int part[16];
    __shared__ int s_prefix;
    int tid = threadIdx.x;
    int lane = tid & 63;
    int w = tid >> 6;                       // [0,16)
    int g = blockIdx.x * 1024 + tid;

    int v = counts[g];
    int x = wave_scan(v, lane);
    if (lane == 63) part[w] = x;
    __syncthreads();
    if (tid < 16) {
        int p = part[tid];
#pragma unroll
        for (int off = 1; off < 16; off <<= 1) {
            int y = __shfl_up(p, off, 64);
            if (tid >= off) p += y;
        }
        part[tid] = p;
    }
    __syncthreads();
    int incl = x + ((w > 0) ? part[w - 1] : 0);
    int total = part[15];                   // block aggregate

    // publish aggregate (block 0 publishes inclusive immediately)
    if (tid == 0) {
        unsigned long long pack = ((unsigned long long)(unsigned)total << 2) |
                                  ((blockIdx.x == 0) ? 2ULL : 1ULL);
        atomicExch(&desc[blockIdx.x], pack);
        if (blockIdx.x == 0) s_prefix = 0;
    }

    // wave-parallel lookback (wave 0 only)
    if (blockIdx.x > 0 && w == 0) {
        int prefix = 0;
        int base = blockIdx.x - 1;
        bool done = false;
        while (!done) {
            int idx = base - lane;          // lane 0 = nearest predecessor
            unsigned long long d = 0;
            if (idx >= 0) {
                do { d = atomicAdd(&desc[idx], 0ULL); } while ((d & 3ULL) == 0ULL);
            }
            unsigned long long mask = __ballot(idx >= 0 && (d & 3ULL) == 2ULL);
            int f = (mask != 0ULL) ? (__ffsll((long long)mask) - 1) : 64;
            int contrib = (idx >= 0 && lane <= f) ? (int)(d >> 2) : 0;
#pragma unroll
            for (int off = 1; off < 64; off <<= 1)
                contrib += __shfl_xor(contrib, off, 64);
            prefix += contrib;
            base -= 64;
            done = (mask != 0ULL);
        }
        if (lane == 0) {
            s_prefix = prefix;
            atomicExch(&desc[blockIdx.x],
                       ((unsigned long long)(unsigned)(prefix + total) << 2) | 2ULL);
        }
    }
    __syncthreads();

    offsets[g] = incl - v + s_prefix;
    if (g == 0) offsets[NBINS] = MPTS;
}

// fill_records: 64B record per point, written to its CSR slot (sorted by bin):
//  [0,12)  w0[6]  f16 axis-0 KB weights
//  [12,24) w1[6]  f16 axis-1 KB weights
//  [24,28) bin1   int (c1 coordinate of the point's bin)
//  [28,32) pad
//  [32,64) y      16 x f16: 8 batches, (re,im) pairs, pre-weighted
__global__ __launch_bounds__(256) void fill_records(
    const float2* __restrict__ uv2,
    const float* __restrict__ y_real, const float* __restrict__ y_imag,
    const float* __restrict__ weights, const int* __restrict__ offsets,
    int* __restrict__ counts, char* __restrict__ rec,
    float beta, float inv_i0b)
{
    int m = blockIdx.x * 256 + threadIdx.x;
    if (m >= MPTS) return;
    float2 u = uv2[m];
    float kf0 = u.x * KF_SCALE;
    float kf1 = u.y * KF_SCALE;
    float f0 = floorf(kf0), f1 = floorf(kf1);
    float fr0 = kf0 - f0, fr1 = kf1 - f1;
    int b1c = (int)f1 & (KK - 1);
    int bin = (((int)f0 & (KK - 1)) << 9) | b1c;
    int old = atomicSub(&counts[bin], 1);
    int slot = offsets[bin] + old - 1;

    _Float16 hw[12];
#pragma unroll
    for (int j = 0; j < JJ; ++j) {
        hw[j]     = (_Float16)kbf((float)(j - 2) - fr0, beta, inv_i0b);
        hw[6 + j] = (_Float16)kbf((float)(j - 2) - fr1, beta, inv_i0b);
    }

    float4 c0v, c1v;
    _Float16* p0 = (_Float16*)&c0v;
    _Float16* p1 = (_Float16*)&c1v;
#pragma unroll
    for (int j = 0; j < 8; ++j) p0[j] = hw[j];        // w0[0..5], w1[0..1]
#pragma unroll
    for (int j = 0; j < 4; ++j) p1[j] = hw[8 + j];    // w1[2..5]
    ((int*)&c1v)[2] = b1c;
    ((int*)&c1v)[3] = 0;

    float wm = weights[m];
    h8 ha, hb;
#pragma unroll
    for (int b = 0; b < 4; ++b) {
        ha[2 * b]     = (_Float16)(y_real[b * MPTS + m] * wm);
        ha[2 * b + 1] = (_Float16)(y_imag[b * MPTS + m] * wm);
        hb[2 * b]     = (_Float16)(y_real[(b + 4) * MPTS + m] * wm);
        hb[2 * b + 1] = (_Float16)(y_imag[(b + 4) * MPTS + m] * wm);
    }

    float4* dst = (float4*)(rec + (size_t)slot * 64);
    dst[0] = c0v;
    dst[1] = c1v;
    dst[2] = *(float4*)&ha;
    dst[3] = *(float4*)&hb;
}

// ---------- gather v5: coalesced LDS staging + per-lane sweep ----------
__global__ __launch_bounds__(256) void gather_grid(
    const int* __restrict__ offsets, const char* __restrict__ rec,
    float* __restrict__ grid)
{
    __shared__ __align__(16) char lds[4][5120];   // 64 pts x 80B per wave
    int t = threadIdx.x;
    int lane = t & 63;
    int w = t >> 6;
    int j = blockIdx.x;
    int xcd = j & 7;
    int slot = j >> 3;                 // [0,128)
    int c0 = (xcd << 6) + (slot >> 1);
    int half = slot & 1;
    int c1base = (half << 8) + (w << 6);
    int c1 = c1base + lane;            // actual column, [0,512)
    int wa = c1 - 3, wb = c1 + 2;      // lane's bin window (unwrapped)

    char* myl = lds[w];

    float aR[BB], aI[BB];
#pragma unroll
    for (int b = 0; b < BB; ++b) { aR[b] = 0.0f; aI[b] = 0.0f; }

    for (int j0 = 0; j0 < JJ; ++j0) {
        int r0 = (c0 - (j0 - 2)) & (KK - 1);
        int rowbase = r0 << 9;
        int lo = c1base - 3, hi = c1base + 65;
        int nseg, ga0, gb0, ga1, gb1;
        if (lo < 0)        { ga0 = lo; gb0 = -1;  ga1 = 0;   gb1 = hi; nseg = 2; }
        else if (hi > 511) { ga0 = lo; gb0 = 511; ga1 = 512; gb1 = hi; nseg = 2; }
        else               { ga0 = lo; gb0 = hi;  ga1 = 0;   gb1 = 0;  nseg = 1; }

        for (int sgi = 0; sgi < nseg; ++sgi) {
            int ga = sgi ? ga1 : ga0;
            int gb = sgi ? gb1 : gb0;
            int pstart = offsets[rowbase + (ga & 511)];          // wave-uniform
            int pend   = offsets[rowbase + ((gb & 511) + 1)];    // wave-uniform
            int ia = max(wa, ga), ib = min(wb, gb);
            bool has = ia <= ib;
            int pA = has ? offsets[rowbase + (ia & 511)] : 0;
            int pB = has ? ((ib == gb) ? pend
                                       : offsets[rowbase + ((ib + 1) & 511)]) : 0;

            for (int pc = pstart; pc < pend; pc += 64) {
                int cnt = min(64, pend - pc);
                int sub = lane & 3;
                int prow = lane >> 2;
#pragma unroll
                for (int q = 0; q < 4; ++q) {
                    if (16 * q < cnt) {
                        int pp = min(pc + prow + 16 * q, MPTS - 1);
                        float4 v = *(const float4*)(rec + (size_t)pp * 64 + sub * 16);
                        *(float4*)(myl + (prow + 16 * q) * 80 + sub * 16) = v;
                    }
                }
                int pLo = max(pA, pc), pHi = min(pB, pc + cnt);
                for (int p = pLo; p < pHi; ++p) {
                    const char* rp = myl + (p - pc) * 80;
                    int bin1 = *(const int*)(rp + 24);
                    int idx = (c1 - bin1 + 2) & 511;   // wrap-exact o1+2
                    bool ok = idx <= 5;
                    idx = ok ? idx : 0;
                    float w0 = (float)*(const _Float16*)(rp + j0 * 2);
                    float w1 = (float)*(const _Float16*)(rp + 12 + idx * 2);
                    float ww = ok ? w0 * w1 : 0.0f;
                    h8 ya = *(const h8*)(rp + 32);
                    h8 yb = *(const h8*)(rp + 48);
#pragma unroll
                    for (int b = 0; b < 4; ++b) {
                        aR[b]     += (float)ya[2 * b]     * ww;   // v_fma_mix
                        aI[b]     += (float)ya[2 * b + 1] * ww;
                        aR[b + 4] += (float)yb[2 * b]     * ww;
                        aI[b + 4] += (float)yb[2 * b + 1] * ww;
                    }
                }
            }
        }
    }

    float2* g2 = (float2*)grid;
    int c = (c0 << 9) + c1;
#pragma unroll
    for (int b = 0; b < BB; ++b)
        g2[((size_t)b << 18) + c] = make_float2(aR[b], aI[b]);
}

// ---------- per-wave 512-pt FFT: 8(reg) x 64(lanes via shfl), sign +i ----------
__device__ __forceinline__ void wave_fft512(float xr[8], float xi[8], int lane)
{
    float a0r = xr[0]+xr[4], a0i = xi[0]+xi[4];
    float a4r = xr[0]-xr[4], a4i = xi[0]-xi[4];
    float a2r = xr[2]+xr[6], a2i = xi[2]+xi[6];
    float a6r = xr[2]-xr[6], a6i = xi[2]-xi[6];
    float a1r = xr[1]+xr[5], a1i = xi[1]+xi[5];
    float a5r = xr[1]-xr[5], a5i = xi[1]-xi[5];
    float a3r = xr[3]+xr[7], a3i = xi[3]+xi[7];
    float a7r = xr[3]-xr[7], a7i = xi[3]-xi[7];
    float b0r = a0r+a2r, b0i = a0i+a2i;
    float b2r = a0r-a2r, b2i = a0i-a2i;
    float b4r = a4r-a6i, b4i = a4i+a6r;    // a4 + i*a6
    float b6r = a4r+a6i, b6i = a4i-a6r;    // a4 - i*a6
    float b1r = a1r+a3r, b1i = a1i+a3i;
    float b3r = a1r-a3r, b3i = a1i-a3i;
    float b5r = a5r-a7i, b5i = a5i+a7r;
    float b7r = a5r+a7i, b7i = a5i-a7r;
    const float S2 = 0.70710678118654752f;
    float w5r = S2*(b5r-b5i), w5i = S2*(b5r+b5i);     // W8^1 * b5
    float w7r = -S2*(b7r+b7i), w7i = S2*(b7r-b7i);    // W8^3 * b7
    float y0r = b0r+b1r, y0i = b0i+b1i;
    float y4r = b0r-b1r, y4i = b0i-b1i;
    float y1r = b4r+w5r, y1i = b4i+w5i;
    float y5r = b4r-w5r, y5i = b4i-w5i;
    float y2r = b2r-b3i, y2i = b2i+b3r;    // b2 + i*b3
    float y6r = b2r+b3i, y6i = b2i-b3r;
    float y3r = b6r+w7r, y3i = b6i+w7i;
    float y7r = b6r-w7r, y7i = b6i-w7i;

    int p = __brev((unsigned)lane) >> 26;
    float ang = (float)(2.0 * M_PI / 512.0) * (float)p;
    float c1, s1; sincosf(ang, &s1, &c1);
    float wr = c1, wi = s1, tr;
    xr[0] = y0r; xi[0] = y0i;
    xr[1] = y1r*wr - y1i*wi; xi[1] = y1i*wr + y1r*wi;
    tr = wr*c1 - wi*s1; wi = wr*s1 + wi*c1; wr = tr;
    xr[2] = y2r*wr - y2i*wi; xi[2] = y2i*wr + y2r*wi;
    tr = wr*c1 - wi*s1; wi = wr*s1 + wi*c1; wr = tr;
    xr[3] = y3r*wr - y3i*wi; xi[3] = y3i*wr + y3r*wi;
    tr = wr*c1 - wi*s1; wi = wr*s1 + wi*c1; wr = tr;
    xr[4] = y4r*wr - y4i*wi; xi[4] = y4i*wr + y4r*wi;
    tr = wr*c1 - wi*s1; wi = wr*s1 + wi*c1; wr = tr;
    xr[5] = y5r*wr - y5i*wi; xi[5] = y5i*wr + y5r*wi;
    tr = wr*c1 - wi*s1; wi = wr*s1 + wi*c1; wr = tr;
    xr[6] = y6r*wr - y6i*wi; xi[6] = y6i*wr + y6r*wi;
    tr = wr*c1 - wi*s1; wi = wr*s1 + wi*c1; wr = tr;
    xr[7] = y7r*wr - y7i*wi; xi[7] = y7i*wr + y7r*wi;

#pragma unroll
    for (int t = 0; t < 6; ++t) {
        int m = 1 << t;
        int j = lane & (m - 1);
        float wc, wsn;
        sincosf((float)M_PI * (float)j / (float)m, &wsn, &wc);  // e^{+2pi i j/(2m)}
        bool hi = (lane & m) != 0;
#pragma unroll
        for (int d = 0; d < 8; ++d) {
            float pR = __shfl_xor(xr[d], m, 64);
            float pI = __shfl_xor(xi[d], m, 64);
            float bR = hi ? xr[d] : pR;
            float bI = hi ? xi[d] : pI;
            float aR = hi ? pR : xr[d];
            float aI = hi ? pI : xi[d];
            float wbR = wc * bR - wsn * bI;
            float wbI = wc * bI + wsn * bR;
            xr[d] = hi ? aR - wbR : aR + wbR;
            xi[d] = hi ? aI - wbI : aI + wbI;
        }
    }
}

// fftA: k2-transform. 512 blocks x 8 waves; wave = row (b, k1).
__global__ __launch_bounds__(512) void fftA(
    const float2* __restrict__ grid2, float2* __restrict__ C)
{
    __shared__ float sR[2112], sI[2112];   // 8 waves * 264, stride33 swizzle
    int t = threadIdx.x;
    int lane = t & 63;
    int w = t >> 6;
    int b = blockIdx.x & 7;
    int k1base = (blockIdx.x >> 3) << 3;
    int k1 = k1base + w;

    const float2* row = grid2 + ((size_t)b << 18) + ((size_t)k1 << 9);
    int p = __brev((unsigned)lane) >> 26;
    float xr[8], xi[8];
#pragma unroll
    for (int a = 0; a < 8; ++a) {
        float2 v = row[p + (a << 6)];
        xr[a] = v.x; xi[a] = v.y;
    }

    wave_fft512(xr, xi, lane);

    bool act = (lane < 16) | (lane >= 48);
    int lpp = (lane < 16) ? lane : (lane - 32);   // [0,32)
    if (act) {
#pragma unroll
        for (int d = 0; d < 8; ++d) {
            int addr = w * 264 + d * 33 + lpp;    // conflict-free swizzle
            sR[addr] = xr[d];
            sI[addr] = xi[d];
        }
    }
    __syncthreads();

#pragma unroll
    for (int pp = 0; pp < 4; ++pp) {
        int idx = pp * 512 + t;                   // [0,2048) = 256 s2 x 8 k1
        int kk = idx & 7;
        int s2 = idx >> 3;
        int v = (s2 + 128) & 255;                 // v = 8*lpp + d
        int d = v & 7;
        int lp = v >> 3;
        int addr = kk * 264 + d * 33 + lp;
        C[(((size_t)(b << 8) + s2) << 9) + k1base + kk] = make_float2(sR[addr], sI[addr]);
    }
}

// fftB: k1-transform + apod + fused min/max; stores img transposed.
__global__ __launch_bounds__(256) void fftB(
    const float2* __restrict__ C, float* __restrict__ imgT, float beta2,
    unsigned* __restrict__ mmin, unsigned* __restrict__ mmax)
{
    int t = threadIdx.x;
    int lane = t & 63;
    int w = t >> 6;
    int rowid = blockIdx.x * 4 + w;               // [0,2048) = b*256 + s2
    int b = rowid >> 8;
    int s2 = rowid & 255;

    const float2* row = C + ((size_t)rowid << 9);
    int p = __brev((unsigned)lane) >> 26;
    float xr[8], xi[8];
#pragma unroll
    for (int a = 0; a < 8; ++a) {
        float2 v = row[p + (a << 6)];
        xr[a] = v.x; xi[a] = v.y;
    }

    wave_fft512(xr, xi, lane);

    const float XF = (float)(M_PI * (double)JJ / (double)KK);
    const float INVK2 = 1.0f / ((float)KK * (float)KK);
    float ns = (float)(s2 - 128);
    float xfs = XF * ns;
    float asq = beta2 - xfs * xfs;
    float ssq = sqrtf(asq);
    float ds = sinhf(ssq) / ssq;                  // wave-uniform
    float sbase = INVK2 / ds;

    bool act = (lane < 16) | (lane >= 48);
    int lpp = (lane < 16) ? lane : (lane - 32);
    float lmin = 1e30f, lmax = -1e30f;
    if (act) {
        float vals[8];
#pragma unroll
        for (int d = 0; d < 8; ++d) {
            int r = (8 * lpp + d + 128) & 255;
            float nr = (float)(r - 128);
            float xfr = XF * nr;
            float arq = beta2 - xfr * xfr;
            float srq = sqrtf(arq);
            float dr = sinhf(srq) / srq;
            float o = xr[d] * sbase / dr;
            vals[d] = o;
            lmin = fminf(lmin, o);
            lmax = fmaxf(lmax, o);
        }
        int r0run = (8 * lpp + 128) & 255;        // 8-run never straddles wrap
        float4* dst = (float4*)(imgT + ((size_t)b << 16) + (s2 << 8) + r0run);
        dst[0] = make_float4(vals[0], vals[1], vals[2], vals[3]);
        dst[1] = make_float4(vals[4], vals[5], vals[6], vals[7]);
    }
#pragma unroll
    for (int off = 32; off >= 1; off >>= 1) {
        lmin = fminf(lmin, __shfl_xor(lmin, off, 64));
        lmax = fmaxf(lmax, __shfl_xor(lmax, off, 64));
    }
    if (lane == 0) {
        atomicMin(&mmin[b], fkey(lmin));
        atomicMax(&mmax[b], fkey(lmax));
    }
}

// norm_t: normalize + transpose imgT[b][s2][r] -> out[b][r][s2].
__global__ __launch_bounds__(256) void norm_t(
    const float* __restrict__ imgT, const unsigned* __restrict__ mmin,
    const unsigned* __restrict__ mmax, float* __restrict__ out)
{
    __shared__ float tile[64][65];
    int b = blockIdx.x >> 4;
    int tl = blockIdx.x & 15;
    int r0 = (tl & 3) << 6;
    int s0 = (tl >> 2) << 6;
    int tr = threadIdx.x & 63;
    int ts = threadIdx.x >> 6;        // [0,4)

    const float* src = imgT + ((size_t)b << 16);
#pragma unroll
    for (int q = 0; q < 16; ++q) {
        int s2 = s0 + (q << 2) + ts;
        tile[s2 - s0][tr] = src[(s2 << 8) + r0 + tr];
    }
    __syncthreads();

    float mn = funkey(mmin[b]);
    float inv = 1.0f / (funkey(mmax[b]) - mn);
    float* dst = out + ((size_t)b << 16);
#pragma unroll
    for (int q = 0; q < 16; ++q) {
        int r = r0 + (q << 2) + ts;
        dst[(r << 8) + s0 + tr] = (tile[tr][r - r0] - mn) * inv;
    }
}

// ---------- host ----------

static double i0_host(double x) {
    double sum = 1.0, term = 1.0;
    double q = x * x * 0.25;
    for (int k = 1; k < 80; ++k) {
        term *= q / ((double)k * (double)k);
        sum += term;
        if (term < sum * 1e-17) break;
    }
    return sum;
}

extern "C" void kernel_launch(void* const* d_in, const int* in_sizes, int n_in,
                              void* d_out, int out_size, void* d_ws, size_t ws_size,
                              hipStream_t stream)
{
    const float* y_real  = (const float*)d_in[0];
    const float* y_imag  = (const float*)d_in[1];
    const float* weights = (const float*)d_in[2];
    const float2* uv2    = (const float2*)d_in[3];
    float* out = (float*)d_out;

    char* W = (char*)d_ws;
    // Aliased live ranges (peak ~24.4 MB):
    //  W[0,16M): counts[1M]+desc[2K] (binning) -> grid (gather->fftA) -> imgT [0,2M)
    //  A=W+16M:  rec [0,6.4M) + offsets [6.4M,7.45M) (bin->gather)
    //            -> C [0,8M) (fftA->fftB);  mm at [8.4M,8.4M+96)
    float*    grid    = (float*)W;                         // 16 MB
    int*      counts  = (int*)W;                           // 1 MB (aliases grid)
    unsigned long long* desc = (unsigned long long*)(W + 0x100000);  // 2 KB
    float*    imgT    = (float*)W;                         // 2 MB (aliases grid)
    char*     A       = W + (size_t)16 * 1024 * 1024;
    char*     rec     = A;                                 // 6,400,000 B
    int*      offsets = (int*)(A + 6400000);               // 1,048,580 B
    float2*   C       = (float2*)A;                        // 8 MB (aliases rec)
    unsigned* mmin    = (unsigned*)(A + 8400000);          // 32 B
    unsigned* mmax    = (unsigned*)(A + 8400064);          // 32 B

    double beta_d = M_PI * sqrt(19.45);   // BETA with alpha=2
    float beta = (float)beta_d;
    float inv_i0b = (float)(1.0 / i0_host(beta_d));
    float beta2 = (float)(beta_d * beta_d);

    // one memset covers counts (1 MB) + desc (2 KB)
    hipMemsetAsync(counts, 0, NBINS * sizeof(int) + 256 * sizeof(unsigned long long),
                   stream);

    count_bins<<<(MPTS + 255) / 256, 256, 0, stream>>>(uv2, counts, mmin, mmax);

    scan_k<<<256, 1024, 0, stream>>>(counts, offsets, desc);

    fill_records<<<(MPTS + 255) / 256, 256, 0, stream>>>(
        uv2, y_real, y_imag, weights, offsets, counts, rec, beta, inv_i0b);

    gather_grid<<<1024, 256, 0, stream>>>(offsets, rec, grid);

    fftA<<<512, 512, 0, stream>>>((const float2*)grid, C);

    fftB<<<512, 256, 0, stream>>>(C, imgT, beta2, mmin, mmax);

    norm_t<<<128, 256, 0, stream>>>(imgT, mmin, mmax, out);
}